// Round 3
// baseline (636.414 us; speedup 1.0000x reference)
//
#include <hip/hip_runtime.h>
#include <hip/hip_bf16.h>

namespace {

constexpr int kB = 8;
constexpr int kE = 32;
constexpr int kHD = 16;
constexpr int kS = 1024;
constexpr int kSUB = 768;
constexpr int kL = 4096;               // P*G
constexpr float kScale = 0.25f;        // HD^-0.5
constexpr float kLamInit = 0.2f;       // 0.8 - 0.6*exp(0)
constexpr float kOutScale = 0.8f;      // 1 - lambda_init

// ---------------------------------------------------------------------------
// Detect mask element layout from byte patterns (values are only 0/1):
//   int32: bytes at off%4!=0 all zero; bytes at off%8 in [4,8) ~50% nonzero
//   u8   : bytes at off%4!=0 ~50% nonzero
//   int64: bytes at off%4!=0 all zero AND bytes at off%8 in [4,8) all zero
// flag: 0 = int32, 1 = u8/bool, 2 = int64
// ---------------------------------------------------------------------------
__global__ void detect_mask_fmt_kernel(const unsigned char* __restrict__ qm,
                                       int* __restrict__ flag) {
  __shared__ int any14, any47;
  if (threadIdx.x == 0) { any14 = 0; any47 = 0; }
  __syncthreads();
  int l14 = 0, l47 = 0;
  for (int i = threadIdx.x; i < 16384; i += 256) {
    const unsigned char v = qm[i];
    if (v && (i & 3)) l14 = 1;
    if (v && ((i & 7) >= 4)) l47 = 1;
  }
  if (l14) atomicOr(&any14, 1);
  if (l47) atomicOr(&any47, 1);
  __syncthreads();
  if (threadIdx.x == 0) *flag = any14 ? 1 : (any47 ? 0 : 2);
}

__device__ __forceinline__ int load_mask(const void* p, long i, int fmt) {
  if (fmt == 1) return (int)((const unsigned char*)p)[i];
  if (fmt == 2) return (int)(((const int*)p)[2 * i] != 0);
  return ((const int*)p)[i];
}

// ---------------------------------------------------------------------------
// Q = (gene_flat @ Wq) * SCALE   — [B*L, 32] @ [32,32]
// ---------------------------------------------------------------------------
__global__ __launch_bounds__(256) void proj_q_kernel(
    const float* __restrict__ query, const float* __restrict__ Wq,
    float* __restrict__ Qout) {
  __shared__ float sW[32][32];
  __shared__ float sX[64][33];
  const int t = threadIdx.x;
  const int base = blockIdx.x * 64 * 32;
  for (int i = t; i < 1024; i += 256) sW[i >> 5][i & 31] = Wq[i];
  for (int i = t; i < 2048; i += 256) sX[i >> 5][i & 31] = query[base + i];
  __syncthreads();
  const int c = t & 31;
  const int r0 = t >> 5;
#pragma unroll
  for (int j = 0; j < 8; ++j) {
    const int r = r0 * 8 + j;
    float acc = 0.f;
#pragma unroll
    for (int k = 0; k < 32; ++k) acc += sX[r][k] * sW[k][c];
    Qout[base + r * 32 + c] = acc * kScale;
  }
}

// ---------------------------------------------------------------------------
// K = key @ Wk, V = key @ Wv — [B*S, 768] @ [768, 32] (x2, fused as 64 cols)
// ---------------------------------------------------------------------------
__global__ __launch_bounds__(256) void proj_kv_kernel(
    const float* __restrict__ key, const float* __restrict__ Wk,
    const float* __restrict__ Wv, float* __restrict__ Kout,
    float* __restrict__ Vout) {
  __shared__ float sKey[16][65];
  __shared__ float sW[64][65];
  const int t = threadIdx.x;
  const int rowbase = blockIdx.x * 16;
  const int c = t & 63;
  const int r0 = t >> 6;
  float acc[4] = {0.f, 0.f, 0.f, 0.f};
  for (int kc = 0; kc < kSUB; kc += 64) {
    __syncthreads();
    for (int i = t; i < 1024; i += 256)
      sKey[i >> 6][i & 63] = key[(rowbase + (i >> 6)) * kSUB + kc + (i & 63)];
    for (int i = t; i < 4096; i += 256) {
      const int kk = i >> 6, cc = i & 63;
      sW[kk][cc] = (cc < 32) ? Wk[(kc + kk) * 32 + cc]
                             : Wv[(kc + kk) * 32 + (cc - 32)];
    }
    __syncthreads();
#pragma unroll
    for (int kk = 0; kk < 64; ++kk) {
      const float w = sW[kk][c];
#pragma unroll
      for (int i = 0; i < 4; ++i) acc[i] += sKey[r0 + 4 * i][kk] * w;
    }
  }
#pragma unroll
  for (int i = 0; i < 4; ++i) {
    const int r = rowbase + r0 + 4 * i;
    if (c < 32) Kout[r * 32 + c] = acc[i];
    else Vout[r * 32 + (c - 32)] = acc[i];
  }
}

// ---------------------------------------------------------------------------
// Fused attention: 8 query rows per block, full S=1024.
// grid: B * (L/8) = 4096 blocks, 256 threads
// ---------------------------------------------------------------------------
__global__ __launch_bounds__(256) void attn_kernel(
    const float* __restrict__ Qm, const float* __restrict__ Km,
    const float* __restrict__ Vm, const void* __restrict__ qmask,
    const void* __restrict__ kmask, const float* __restrict__ lq1,
    const float* __restrict__ lk1, const float* __restrict__ lq2,
    const float* __restrict__ lk2, const float* __restrict__ rmsw,
    const float* __restrict__ Wo, const int* __restrict__ mflag,
    float* __restrict__ out, float* __restrict__ diff) {
  __shared__ float dT[8][kS];     // 32 KB: d values, later final diff
  __shared__ float Ks[64][33];    // K tile (reused for V tile)
  __shared__ float Qs[8][33];
  __shared__ float aos[8][32];
  __shared__ int kmS[kS];
  __shared__ float sWo[32][32];
  __shared__ float srw[32];
  __shared__ float sm[8][2];
  __shared__ float sinv[8][2];
  __shared__ float rowmin[8];
  __shared__ int qmS[8];
  __shared__ float slam;

  const int t = threadIdx.x;
  const int b = blockIdx.x >> 9;
  const int l0 = (blockIdx.x & 511) * 8;
  const int rowbase = b * kL + l0;  // global gene row
  const int kvbase = b * kS;        // global key row
  const int fmt = *mflag;

  // ---- stage per-block constants ----
  for (int i = t; i < kS; i += 256)
    kmS[i] = load_mask(kmask, (long)b * kS + i, fmt);
  for (int i = t; i < 8 * 32; i += 256) Qs[i >> 5][i & 31] = Qm[rowbase * 32 + i];
  for (int i = t; i < 1024; i += 256) sWo[i >> 5][i & 31] = Wo[i];
  if (t < 32) srw[t] = rmsw[t];
  if (t < 8) qmS[t] = load_mask(qmask, (long)rowbase + t, fmt);
  if (t == 0) {
    float a = 0.f, c2 = 0.f;
#pragma unroll
    for (int i = 0; i < kHD; ++i) {
      a += lq1[i] * lk1[i];
      c2 += lq2[i] * lk2[i];
    }
    slam = expf(a) - expf(c2) + kLamInit;
  }
  __syncthreads();

  // ---- Phase A: per-(row,head) running max + sumexp over S ----
  {
    const int rh = t >> 4, slot = t & 15;
    const int row = rh >> 1, h = rh & 1;
    float m = -3.0e38f, se = 0.f;
    for (int sc = 0; sc < kS; sc += 64) {
      for (int i = t; i < 2048; i += 256)
        Ks[i >> 5][i & 31] = Km[(kvbase + sc) * 32 + i];
      __syncthreads();
#pragma unroll
      for (int i = 0; i < 4; ++i) {
        const int sl = slot + 16 * i;
        float sc0 = 0.f;
#pragma unroll
        for (int d = 0; d < kHD; ++d)
          sc0 += Qs[row][h * kHD + d] * Ks[sl][h * kHD + d];
        const float val = kmS[sc + sl] ? sc0 : -1e20f;
        if (val > m) {
          se = se * expf(m - val) + 1.f;
          m = val;
        } else {
          se += expf(val - m);
        }
      }
      __syncthreads();
    }
    for (int off = 8; off >= 1; off >>= 1) {
      const float m2 = __shfl_xor(m, off);
      const float s2 = __shfl_xor(se, off);
      const float nm = fmaxf(m, m2);
      se = se * expf(m - nm) + s2 * expf(m2 - nm);
      m = nm;
    }
    if (slot == 0) {
      sm[row][h] = m;
      sinv[row][h] = 1.f / (se + 1e-8f);
    }
  }
  __syncthreads();

  // ---- Phase B: d = a0 - lam*a1 into LDS, track row min ----
  const int rowB = t >> 5, slotB = t & 31;
  float dmin = 3.0e38f;
  {
    const float m0 = sm[rowB][0], m1 = sm[rowB][1];
    const float i0 = sinv[rowB][0], i1 = sinv[rowB][1];
    const float lam = slam;
    for (int sc = 0; sc < kS; sc += 64) {
      __syncthreads();
      for (int i = t; i < 2048; i += 256)
        Ks[i >> 5][i & 31] = Km[(kvbase + sc) * 32 + i];
      __syncthreads();
#pragma unroll
      for (int i = 0; i < 2; ++i) {
        const int sl = slotB + 32 * i;
        float s0 = 0.f, s1 = 0.f;
#pragma unroll
        for (int d = 0; d < kHD; ++d) {
          s0 += Qs[rowB][d] * Ks[sl][d];
          s1 += Qs[rowB][kHD + d] * Ks[sl][kHD + d];
        }
        const int km = kmS[sc + sl];
        const float v0 = km ? s0 : -1e20f;
        const float v1 = km ? s1 : -1e20f;
        const float a0 = expf(v0 - m0) * i0;
        const float a1 = expf(v1 - m1) * i1;
        const float dv = a0 - lam * a1;
        dT[rowB][sc + sl] = dv;
        dmin = fminf(dmin, dv);
      }
    }
  }
  for (int off = 16; off >= 1; off >>= 1) dmin = fminf(dmin, __shfl_xor(dmin, off));
  if (slotB == 0) rowmin[rowB] = dmin;
  __syncthreads();

  // ---- Phase C: masked min-shift, write diff output (fp32) ----
  for (int idx = t; idx < 8 * kS; idx += 256) {
    const int row = idx >> 10, s = idx & (kS - 1);
    float fd = 0.f;
    if (qmS[row] && kmS[s]) fd = dT[row][s] - rowmin[row] + 1e-5f;
    dT[row][s] = fd;
    diff[(long)(rowbase + row) * kS + s] = fd;
  }
  __syncthreads();

  // ---- Phase D: attn_out = diff @ V ----
  {
    const int row = t >> 5, e = t & 31;
    float acc = 0.f;
    for (int sc = 0; sc < kS; sc += 64) {
      __syncthreads();
      for (int i = t; i < 2048; i += 256)
        Ks[i >> 5][i & 31] = Vm[(kvbase + sc) * 32 + i];
      __syncthreads();
#pragma unroll
      for (int sl = 0; sl < 64; ++sl) acc += dT[row][sc + sl] * Ks[sl][e];
    }
    aos[row][e] = acc;
  }
  __syncthreads();

  // ---- Phase E: RMSNorm + scale + @Wo, write out (fp32) ----
  {
    const int row = t >> 5, c = t & 31;
    const float x = aos[row][c];
    float ss = x * x;
    for (int off = 16; off >= 1; off >>= 1) ss += __shfl_xor(ss, off);
    const float rms = 1.0f / sqrtf(ss * (1.f / 32.f) + 1e-5f);
    const float nx = x * rms * srw[c] * kOutScale;
    __syncthreads();
    aos[row][c] = nx;
    __syncthreads();
    float acc = 0.f;
#pragma unroll
    for (int e = 0; e < 32; ++e) acc += aos[row][e] * sWo[e][c];
    out[(long)(rowbase + row) * 32 + c] = acc;
  }
}

}  // namespace

extern "C" void kernel_launch(void* const* d_in, const int* in_sizes, int n_in,
                              void* d_out, int out_size, void* d_ws,
                              size_t ws_size, hipStream_t stream) {
  const float* query = (const float*)d_in[0];
  const float* key = (const float*)d_in[1];
  const void* qmask = d_in[2];
  const void* kmask = d_in[3];
  const float* Wq = (const float*)d_in[4];
  const float* Wk = (const float*)d_in[5];
  const float* Wv = (const float*)d_in[6];
  const float* Wo = (const float*)d_in[7];
  const float* lq1 = (const float*)d_in[8];
  const float* lk1 = (const float*)d_in[9];
  const float* lq2 = (const float*)d_in[10];
  const float* lk2 = (const float*)d_in[11];
  const float* rmsw = (const float*)d_in[12];

  float* Qw = (float*)d_ws;                       // [B*L, 32]
  float* Kw = Qw + (size_t)kB * kL * kE;          // [B*S, 32]
  float* Vw = Kw + (size_t)kB * kS * kE;          // [B*S, 32]
  int* mflag = (int*)(Vw + (size_t)kB * kS * kE);

  float* outp = (float*)d_out;
  float* diffp = outp + (size_t)kB * kL * kE;

  detect_mask_fmt_kernel<<<dim3(1), dim3(256), 0, stream>>>(
      (const unsigned char*)qmask, mflag);
  proj_q_kernel<<<dim3(kB * kL / 64), dim3(256), 0, stream>>>(query, Wq, Qw);
  proj_kv_kernel<<<dim3(kB * kS / 16), dim3(256), 0, stream>>>(key, Wk, Wv, Kw,
                                                               Vw);
  attn_kernel<<<dim3(kB * (kL / 8)), dim3(256), 0, stream>>>(
      Qw, Kw, Vw, qmask, kmask, lq1, lk1, lq2, lk2, rmsw, Wo, mflag, outp,
      diffp);
}

// Round 4
// 228.518 us; speedup vs baseline: 2.7850x; 2.7850x over previous
//
#include <hip/hip_runtime.h>

namespace {

typedef __attribute__((ext_vector_type(8))) short short8v;
typedef __attribute__((ext_vector_type(4))) float f32x4;

constexpr int kB = 8;
constexpr int kS = 1024;
constexpr int kSUB = 768;
constexpr int kL = 4096;                                   // P*G
constexpr float kQScale = 0.25f * 1.44269504088896340736f; // SCALING*log2(e)
constexpr float kLamInit = 0.2f;
constexpr float kOutScale = 0.8f;
constexpr float kNegBig = -1e20f;

__device__ __forceinline__ unsigned short f2bf(float x) {
  unsigned u = __float_as_uint(x);
  return (unsigned short)((u + 0x7FFFu + ((u >> 16) & 1u)) >> 16);
}

__device__ __forceinline__ float fast_exp2(float x) {
#if __has_builtin(__builtin_amdgcn_exp2f)
  return __builtin_amdgcn_exp2f(x);
#else
  return exp2f(x);
#endif
}

// ---------------------------------------------------------------------------
// Mask layout detection (values 0/1 only). flag: 0=int32, 1=u8, 2=int64
// ---------------------------------------------------------------------------
__global__ void detect_mask_fmt_kernel(const unsigned char* __restrict__ qm,
                                       int* __restrict__ flag) {
  __shared__ int any14, any47;
  if (threadIdx.x == 0) { any14 = 0; any47 = 0; }
  __syncthreads();
  int l14 = 0, l47 = 0;
  for (int i = threadIdx.x; i < 16384; i += 256) {
    const unsigned char v = qm[i];
    if (v && (i & 3)) l14 = 1;
    if (v && ((i & 7) >= 4)) l47 = 1;
  }
  if (l14) atomicOr(&any14, 1);
  if (l47) atomicOr(&any47, 1);
  __syncthreads();
  if (threadIdx.x == 0) *flag = any14 ? 1 : (any47 ? 0 : 2);
}

__device__ __forceinline__ int load_mask(const void* p, long i, int fmt) {
  if (fmt == 1) return (int)((const unsigned char*)p)[i];
  if (fmt == 2) return (int)(((const int*)p)[2 * i] != 0);
  return ((const int*)p)[i];
}

// ---------------------------------------------------------------------------
// Qbf = bf16((gene_flat @ Wq) * SCALE * log2e)   — [B*L, 32] @ [32,32]
// ---------------------------------------------------------------------------
__global__ __launch_bounds__(256) void proj_q_kernel(
    const float* __restrict__ query, const float* __restrict__ Wq,
    unsigned short* __restrict__ Qbf) {
  __shared__ float sW[32][32];
  __shared__ float sX[64][33];
  const int t = threadIdx.x;
  const int base = blockIdx.x * 64 * 32;
  for (int i = t; i < 1024; i += 256) sW[i >> 5][i & 31] = Wq[i];
  for (int i = t; i < 2048; i += 256) sX[i >> 5][i & 31] = query[base + i];
  __syncthreads();
  const int c = t & 31;
  const int r0 = t >> 5;
#pragma unroll
  for (int j = 0; j < 8; ++j) {
    const int r = r0 * 8 + j;
    float acc = 0.f;
#pragma unroll
    for (int k = 0; k < 32; ++k) acc += sX[r][k] * sW[k][c];
    Qbf[base + r * 32 + c] = f2bf(acc * kQScale);
  }
}

// ---------------------------------------------------------------------------
// Kbf[b*S+s][e] = bf16(key@Wk);  Vt[b][e][s] = bf16(key@Wv) (transposed)
// ---------------------------------------------------------------------------
__global__ __launch_bounds__(256) void proj_kv_kernel(
    const float* __restrict__ key, const float* __restrict__ Wk,
    const float* __restrict__ Wv, unsigned short* __restrict__ Kbf,
    unsigned short* __restrict__ Vt) {
  __shared__ float sKey[16][65];
  __shared__ float sW[64][65];
  const int t = threadIdx.x;
  const int rowbase = blockIdx.x * 16;
  const int c = t & 63;
  const int r0 = t >> 6;
  float acc[4] = {0.f, 0.f, 0.f, 0.f};
  for (int kc = 0; kc < kSUB; kc += 64) {
    __syncthreads();
    for (int i = t; i < 1024; i += 256)
      sKey[i >> 6][i & 63] = key[(rowbase + (i >> 6)) * kSUB + kc + (i & 63)];
    for (int i = t; i < 4096; i += 256) {
      const int kk = i >> 6, cc = i & 63;
      sW[kk][cc] = (cc < 32) ? Wk[(kc + kk) * 32 + cc]
                             : Wv[(kc + kk) * 32 + (cc - 32)];
    }
    __syncthreads();
#pragma unroll
    for (int kk = 0; kk < 64; ++kk) {
      const float w = sW[kk][c];
#pragma unroll
      for (int i = 0; i < 4; ++i) acc[i] += sKey[r0 + 4 * i][kk] * w;
    }
  }
#pragma unroll
  for (int i = 0; i < 4; ++i) {
    const int r = rowbase + r0 + 4 * i;
    if (c < 32) {
      Kbf[(size_t)r * 32 + c] = f2bf(acc[i]);
    } else {
      const int bb = r >> 10, s = r & 1023;
      Vt[((size_t)bb * 32 + (c - 32)) * kS + s] = f2bf(acc[i]);
    }
  }
}

// ---------------------------------------------------------------------------
// Fused MFMA attention: 16 query rows/block, 512 threads (8 waves x 128 cols)
// grid: B * (L/16) = 2048 blocks
// ---------------------------------------------------------------------------
__global__ __launch_bounds__(512) void attn_kernel(
    const unsigned short* __restrict__ Qbf,
    const unsigned short* __restrict__ Kbf,
    const unsigned short* __restrict__ Vt, const void* __restrict__ qmask,
    const void* __restrict__ kmask, const float* __restrict__ lq1,
    const float* __restrict__ lk1, const float* __restrict__ lq2,
    const float* __restrict__ lk2, const float* __restrict__ rmsw,
    const float* __restrict__ Wo, const int* __restrict__ mflag,
    float* __restrict__ out, float* __restrict__ diff) {
  __shared__ unsigned short dlds[16 * 1040];  // d' bf16, padded stride
  __shared__ float pvred[8][16][33];
  __shared__ int kmS[kS];
  __shared__ float sWo[32][32];
  __shared__ float aos[16][33];
  __shared__ float redm[8][2][16];
  __shared__ float reds[8][2][16];
  __shared__ float redn[8][16];
  __shared__ float srw[32];
  __shared__ int qmS[16];
  __shared__ float slam;

  const int t = threadIdx.x;
  const int lane = t & 63;
  const int w = t >> 6;
  const int r15 = lane & 15;
  const int g = lane >> 4;  // 0..3 (k-group / C-row-group)
  const int b = blockIdx.x >> 8;
  const int rt = (blockIdx.x & 255) * 16;
  const int rowbase = b * kL + rt;
  const int kvb = b * kS;
  const int fmt = *mflag;

  for (int i = t; i < kS; i += 512) kmS[i] = load_mask(kmask, (long)kvb + i, fmt);
  for (int i = t; i < 1024; i += 512) sWo[i >> 5][i & 31] = Wo[i];
  if (t < 32) srw[t] = rmsw[t];
  if (t < 16) qmS[t] = load_mask(qmask, (long)rowbase + t, fmt);
  if (t == 0) {
    float a = 0.f, c2 = 0.f;
#pragma unroll
    for (int i = 0; i < 16; ++i) {
      a += lq1[i] * lk1[i];
      c2 += lq2[i] * lk2[i];
    }
    slam = expf(a) - expf(c2) + kLamInit;
  }
  __syncthreads();

  const int wb = w * 128;  // this wave's S-range base
  const short8v z8 = {0, 0, 0, 0, 0, 0, 0, 0};
  const f32x4 zf = {0.f, 0.f, 0.f, 0.f};

  // ---- A fragments: Q rows (lanes<32 hold k=0..15; lanes>=32 zero) ----
  short8v qa[2] = {z8, z8};
  if (lane < 32) {
#pragma unroll
    for (int h = 0; h < 2; ++h)
      qa[h] = *(const short8v*)&Qbf[((size_t)(rowbase + r15)) * 32 + h * 16 + g * 8];
  }

  // ---- QK^T via MFMA: 8 chunks x 2 heads; C: col=lane&15, row=g*4+j ----
  f32x4 acc[8][2];
#pragma unroll
  for (int c = 0; c < 8; ++c) {
#pragma unroll
    for (int h = 0; h < 2; ++h) {
      short8v kb = z8;
      if (lane < 32)
        kb = *(const short8v*)&Kbf[((size_t)(kvb + wb + c * 16 + r15)) * 32 +
                                   h * 16 + g * 8];
      acc[c][h] = __builtin_amdgcn_mfma_f32_16x16x32_bf16(qa[h], kb, zf, 0, 0, 0);
    }
  }

  int kmv[8];
#pragma unroll
  for (int c = 0; c < 8; ++c) kmv[c] = kmS[wb + c * 16 + r15];

  // ---- row max (2-level: shfl within wave, LDS across 8 waves) ----
  float fm[2][4];
  {
#pragma unroll
    for (int h = 0; h < 2; ++h)
#pragma unroll
      for (int j = 0; j < 4; ++j) {
        float m = -3.0e38f;
#pragma unroll
        for (int c = 0; c < 8; ++c) m = fmaxf(m, kmv[c] ? acc[c][h][j] : kNegBig);
#pragma unroll
        for (int off = 8; off >= 1; off >>= 1) m = fmaxf(m, __shfl_xor(m, off));
        if (r15 == 0) redm[w][h][g * 4 + j] = m;
      }
  }
  __syncthreads();
#pragma unroll
  for (int h = 0; h < 2; ++h)
#pragma unroll
    for (int j = 0; j < 4; ++j) {
      float m = -3.0e38f;
#pragma unroll
      for (int ww = 0; ww < 8; ++ww) m = fmaxf(m, redm[ww][h][g * 4 + j]);
      fm[h][j] = m;
    }

  // ---- exp2 in place + row sum ----
  float fi[2][4];
#pragma unroll
  for (int h = 0; h < 2; ++h)
#pragma unroll
    for (int j = 0; j < 4; ++j) {
      float s = 0.f;
#pragma unroll
      for (int c = 0; c < 8; ++c) {
        const float v = kmv[c] ? acc[c][h][j] : kNegBig;
        const float e = fast_exp2(v - fm[h][j]);
        acc[c][h][j] = e;
        s += e;
      }
#pragma unroll
      for (int off = 8; off >= 1; off >>= 1) s += __shfl_xor(s, off);
      if (r15 == 0) reds[w][h][g * 4 + j] = s;
    }
  __syncthreads();
#pragma unroll
  for (int h = 0; h < 2; ++h)
#pragma unroll
    for (int j = 0; j < 4; ++j) {
      float s = 0.f;
#pragma unroll
      for (int ww = 0; ww < 8; ++ww) s += reds[ww][h][g * 4 + j];
      fi[h][j] = 1.f / (s + 1e-8f);
    }

  // ---- d = a0 - lam*a1 (in place, head0 slot) + row min ----
  const float lam = slam;
  float rmin[4];
#pragma unroll
  for (int j = 0; j < 4; ++j) {
    float dm = 3.0e38f;
#pragma unroll
    for (int c = 0; c < 8; ++c) {
      const float d = acc[c][0][j] * fi[0][j] - lam * acc[c][1][j] * fi[1][j];
      acc[c][0][j] = d;
      dm = fminf(dm, d);
    }
#pragma unroll
    for (int off = 8; off >= 1; off >>= 1) dm = fminf(dm, __shfl_xor(dm, off));
    if (r15 == 0) redn[w][g * 4 + j] = dm;
  }
  __syncthreads();
#pragma unroll
  for (int j = 0; j < 4; ++j) {
    float m = 3.0e38f;
#pragma unroll
    for (int ww = 0; ww < 8; ++ww) m = fminf(m, redn[ww][g * 4 + j]);
    rmin[j] = m;
  }

  // ---- final diff: write global fp32 + stage bf16 in LDS for PV ----
#pragma unroll
  for (int c = 0; c < 8; ++c) {
#pragma unroll
    for (int j = 0; j < 4; ++j) {
      const int row = g * 4 + j;
      const int scol = wb + c * 16 + r15;
      float fd = 0.f;
      if (qmS[row] && kmv[c]) fd = acc[c][0][j] - rmin[j] + 1e-5f;
      diff[((size_t)(rowbase + row)) * kS + scol] = fd;
      dlds[row * 1040 + scol] = f2bf(fd);
    }
  }
  __syncthreads();

  // ---- PV via MFMA: A = d' (16 x 128 per wave), B = Vt chunks ----
  f32x4 pv[2] = {zf, zf};
#pragma unroll
  for (int kc = 0; kc < 4; ++kc) {
    const int soff = wb + kc * 32 + g * 8;
    const short8v av = *(const short8v*)&dlds[r15 * 1040 + soff];
#pragma unroll
    for (int n = 0; n < 2; ++n) {
      const short8v bv =
          *(const short8v*)&Vt[((size_t)(b * 32 + n * 16 + r15)) * kS + soff];
      pv[n] = __builtin_amdgcn_mfma_f32_16x16x32_bf16(av, bv, pv[n], 0, 0, 0);
    }
  }
#pragma unroll
  for (int n = 0; n < 2; ++n)
#pragma unroll
    for (int j = 0; j < 4; ++j) pvred[w][g * 4 + j][n * 16 + r15] = pv[n][j];
  __syncthreads();

  // ---- epilogue: reduce 8 waves, RMSNorm, @Wo ----
  {
    const int row = t >> 5;
    const int col = t & 31;
    float ao = 0.f;
#pragma unroll
    for (int ww = 0; ww < 8; ++ww) ao += pvred[ww][row][col];
    float ss = ao * ao;
#pragma unroll
    for (int off = 16; off >= 1; off >>= 1) ss += __shfl_xor(ss, off);
    const float rms = 1.0f / sqrtf(ss * (1.f / 32.f) + 1e-5f);
    aos[row][col] = ao * rms * srw[col] * kOutScale;
  }
  __syncthreads();
  {
    const int row = t >> 5;
    const int col = t & 31;
    float o = 0.f;
#pragma unroll
    for (int e = 0; e < 32; ++e) o += aos[row][e] * sWo[e][col];
    out[((size_t)(rowbase + row)) * 32 + col] = o;
  }
}

}  // namespace

extern "C" void kernel_launch(void* const* d_in, const int* in_sizes, int n_in,
                              void* d_out, int out_size, void* d_ws,
                              size_t ws_size, hipStream_t stream) {
  const float* query = (const float*)d_in[0];
  const float* key = (const float*)d_in[1];
  const void* qmask = d_in[2];
  const void* kmask = d_in[3];
  const float* Wq = (const float*)d_in[4];
  const float* Wk = (const float*)d_in[5];
  const float* Wv = (const float*)d_in[6];
  const float* Wo = (const float*)d_in[7];
  const float* lq1 = (const float*)d_in[8];
  const float* lk1 = (const float*)d_in[9];
  const float* lq2 = (const float*)d_in[10];
  const float* lk2 = (const float*)d_in[11];
  const float* rmsw = (const float*)d_in[12];

  unsigned short* Qbf = (unsigned short*)d_ws;            // [B*L,32] bf16
  unsigned short* Kbf = Qbf + (size_t)kB * kL * 32;       // [B*S,32] bf16
  unsigned short* Vt = Kbf + (size_t)kB * kS * 32;        // [B,32,S] bf16
  int* mflag = (int*)(Vt + (size_t)kB * kS * 32);

  float* outp = (float*)d_out;
  float* diffp = outp + (size_t)kB * kL * 32;

  detect_mask_fmt_kernel<<<dim3(1), dim3(256), 0, stream>>>(
      (const unsigned char*)qmask, mflag);
  proj_q_kernel<<<dim3(kB * kL / 64), dim3(256), 0, stream>>>(query, Wq, Qbf);
  proj_kv_kernel<<<dim3(kB * kS / 16), dim3(256), 0, stream>>>(key, Wk, Wv,
                                                               Kbf, Vt);
  attn_kernel<<<dim3(kB * (kL / 16)), dim3(512), 0, stream>>>(
      Qbf, Kbf, Vt, qmask, kmask, lq1, lk1, lq2, lk2, rmsw, Wo, mflag, outp,
      diffp);
}

// Round 5
// 159.157 us; speedup vs baseline: 3.9987x; 1.4358x over previous
//
#include <hip/hip_runtime.h>

namespace {

typedef __attribute__((ext_vector_type(8))) short short8v;
typedef __attribute__((ext_vector_type(4))) float f32x4;
typedef __attribute__((ext_vector_type(2))) unsigned int uint2v;

constexpr int kB = 8;
constexpr int kS = 1024;
constexpr int kSUB = 768;
constexpr int kL = 4096;                                   // P*G
constexpr float kQScale = 0.25f * 1.44269504088896340736f; // SCALING*log2(e)
constexpr float kLamInit = 0.2f;
constexpr float kOutScale = 0.8f;
constexpr float kNegBig = -1e20f;

__device__ __forceinline__ unsigned short f2bf(float x) {
  unsigned u = __float_as_uint(x);
  return (unsigned short)((u + 0x7FFFu + ((u >> 16) & 1u)) >> 16);
}

__device__ __forceinline__ float fast_exp2(float x) {
#if __has_builtin(__builtin_amdgcn_exp2f)
  return __builtin_amdgcn_exp2f(x);
#else
  return exp2f(x);
#endif
}

// ---------------------------------------------------------------------------
// Mask layout detection (values 0/1 only). flag: 0=int32, 1=u8, 2=int64
// ---------------------------------------------------------------------------
__global__ void detect_mask_fmt_kernel(const unsigned char* __restrict__ qm,
                                       int* __restrict__ flag) {
  __shared__ int any14, any47;
  if (threadIdx.x == 0) { any14 = 0; any47 = 0; }
  __syncthreads();
  int l14 = 0, l47 = 0;
  for (int i = threadIdx.x; i < 16384; i += 256) {
    const unsigned char v = qm[i];
    if (v && (i & 3)) l14 = 1;
    if (v && ((i & 7) >= 4)) l47 = 1;
  }
  if (l14) atomicOr(&any14, 1);
  if (l47) atomicOr(&any47, 1);
  __syncthreads();
  if (threadIdx.x == 0) *flag = any14 ? 1 : (any47 ? 0 : 2);
}

__device__ __forceinline__ int load_mask(const void* p, long i, int fmt) {
  if (fmt == 1) return (int)((const unsigned char*)p)[i];
  if (fmt == 2) return (int)(((const int*)p)[2 * i] != 0);
  return ((const int*)p)[i];
}

// ---------------------------------------------------------------------------
// Weight prep: WkT/WvT[c][k] = bf16(W[k][c])  (c<32, k<768)
// ---------------------------------------------------------------------------
__global__ __launch_bounds__(256) void prep_wt_kernel(
    const float* __restrict__ Wk, const float* __restrict__ Wv,
    unsigned short* __restrict__ WkT, unsigned short* __restrict__ WvT) {
  int idx = blockIdx.x * 256 + threadIdx.x;
  if (idx < 24576) {
    const int k = idx >> 5, c = idx & 31;
    WkT[c * 768 + k] = f2bf(Wk[idx]);
  } else {
    idx -= 24576;
    const int k = idx >> 5, c = idx & 31;
    WvT[c * 768 + k] = f2bf(Wv[idx]);
  }
}

// ---------------------------------------------------------------------------
// Qbf = bf16((query @ Wq) * SCALE*log2e) via MFMA. 64 rows/block, 256 thr.
// ---------------------------------------------------------------------------
__global__ __launch_bounds__(256) void proj_q_kernel(
    const float* __restrict__ query, const float* __restrict__ Wq,
    unsigned short* __restrict__ Qbf) {
  __shared__ unsigned short wqT[32][32];  // [col][k], scaled
  const int t = threadIdx.x;
  for (int i = t; i < 1024; i += 256) {
    const int k = i >> 5, c = i & 31;
    wqT[c][k] = f2bf(Wq[i] * kQScale);
  }
  __syncthreads();
  const int lane = t & 63, w = t >> 6;
  const int r15 = lane & 15, g = lane >> 4;
  const int row = blockIdx.x * 64 + w * 16 + r15;
  const f32x4 zf = {0.f, 0.f, 0.f, 0.f};
  f32x4 lo = *(const f32x4*)&query[(size_t)row * 32 + g * 8];
  f32x4 hi = *(const f32x4*)&query[(size_t)row * 32 + g * 8 + 4];
  short8v a;
#pragma unroll
  for (int j = 0; j < 4; ++j) {
    a[j] = (short)f2bf(lo[j]);
    a[4 + j] = (short)f2bf(hi[j]);
  }
  const short8v b0 = *(const short8v*)&wqT[r15][g * 8];
  const short8v b1 = *(const short8v*)&wqT[16 + r15][g * 8];
  const f32x4 c0 = __builtin_amdgcn_mfma_f32_16x16x32_bf16(a, b0, zf, 0, 0, 0);
  const f32x4 c1 = __builtin_amdgcn_mfma_f32_16x16x32_bf16(a, b1, zf, 0, 0, 0);
  const int orow = blockIdx.x * 64 + w * 16 + g * 4;
#pragma unroll
  for (int jj = 0; jj < 4; ++jj) {
    Qbf[(size_t)(orow + jj) * 32 + r15] = f2bf(c0[jj]);
    Qbf[(size_t)(orow + jj) * 32 + 16 + r15] = f2bf(c1[jj]);
  }
}

// ---------------------------------------------------------------------------
// K/V projection via MFMA: 64 rows/block, 256 threads, K=768 in 24 steps.
// Kbf[r][e]; Vt[b][e][s].
// ---------------------------------------------------------------------------
__global__ __launch_bounds__(256) void proj_kv_kernel(
    const float* __restrict__ key, const unsigned short* __restrict__ WkT,
    const unsigned short* __restrict__ WvT, unsigned short* __restrict__ Kbf,
    unsigned short* __restrict__ Vt) {
  const int t = threadIdx.x, lane = t & 63, w = t >> 6;
  const int r15 = lane & 15, g = lane >> 4;
  const int row = blockIdx.x * 64 + w * 16 + r15;
  const float* kp = &key[(size_t)row * kSUB];
  const f32x4 zf = {0.f, 0.f, 0.f, 0.f};
  f32x4 aK0 = zf, aK1 = zf, aV0 = zf, aV1 = zf;
#pragma unroll 4
  for (int ks = 0; ks < kSUB; ks += 32) {
    const f32x4 lo = *(const f32x4*)&kp[ks + g * 8];
    const f32x4 hi = *(const f32x4*)&kp[ks + g * 8 + 4];
    short8v a;
#pragma unroll
    for (int j = 0; j < 4; ++j) {
      a[j] = (short)f2bf(lo[j]);
      a[4 + j] = (short)f2bf(hi[j]);
    }
    const short8v bk0 = *(const short8v*)&WkT[(size_t)r15 * 768 + ks + g * 8];
    const short8v bk1 =
        *(const short8v*)&WkT[(size_t)(16 + r15) * 768 + ks + g * 8];
    const short8v bv0 = *(const short8v*)&WvT[(size_t)r15 * 768 + ks + g * 8];
    const short8v bv1 =
        *(const short8v*)&WvT[(size_t)(16 + r15) * 768 + ks + g * 8];
    aK0 = __builtin_amdgcn_mfma_f32_16x16x32_bf16(a, bk0, aK0, 0, 0, 0);
    aK1 = __builtin_amdgcn_mfma_f32_16x16x32_bf16(a, bk1, aK1, 0, 0, 0);
    aV0 = __builtin_amdgcn_mfma_f32_16x16x32_bf16(a, bv0, aV0, 0, 0, 0);
    aV1 = __builtin_amdgcn_mfma_f32_16x16x32_bf16(a, bv1, aV1, 0, 0, 0);
  }
  const int orow = blockIdx.x * 64 + w * 16 + g * 4;
#pragma unroll
  for (int jj = 0; jj < 4; ++jj) {
    const int r = orow + jj;
    Kbf[(size_t)r * 32 + r15] = f2bf(aK0[jj]);
    Kbf[(size_t)r * 32 + 16 + r15] = f2bf(aK1[jj]);
    const int bb = r >> 10, s = r & 1023;
    Vt[((size_t)bb * 32 + r15) * kS + s] = f2bf(aV0[jj]);
    Vt[((size_t)bb * 32 + 16 + r15) * kS + s] = f2bf(aV1[jj]);
  }
}

// ---------------------------------------------------------------------------
// Fused MFMA attention (swapped QK: D[s][q]); 16 q-rows/block, 512 threads.
// grid: B * (L/16) = 2048 blocks
// ---------------------------------------------------------------------------
__global__ __launch_bounds__(512) void attn_kernel(
    const unsigned short* __restrict__ Qbf,
    const unsigned short* __restrict__ Kbf,
    const unsigned short* __restrict__ Vt, const void* __restrict__ qmask,
    const void* __restrict__ kmask, const float* __restrict__ lq1,
    const float* __restrict__ lk1, const float* __restrict__ lq2,
    const float* __restrict__ lk2, const float* __restrict__ rmsw,
    const float* __restrict__ Wo, const int* __restrict__ mflag,
    float* __restrict__ out, float* __restrict__ diff) {
  __shared__ unsigned short dlds[16 * 1040];  // [q][s] bf16, padded
  __shared__ float pvred[8][16][34];
  __shared__ float sWo[32][32];
  __shared__ float aos[16][33];
  __shared__ unsigned kmp_lds[256];           // 4 mask bytes per word
  __shared__ float redm[8][2][16];
  __shared__ float reds[8][2][16];
  __shared__ float redn[8][16];
  __shared__ float srw[32];
  __shared__ int qmS[16];
  __shared__ float slam;

  const int t = threadIdx.x;
  const int lane = t & 63;
  const int w = t >> 6;
  const int r15 = lane & 15;
  const int g = lane >> 4;
  const int b = blockIdx.x >> 8;
  const int rt = (blockIdx.x & 255) * 16;
  const int rowbase = b * kL + rt;
  const int kvb = b * kS;
  const int fmt = *mflag;

  if (t < 256) {
    const long base = (long)kvb + 4 * t;
    const unsigned m0 = load_mask(kmask, base + 0, fmt) ? 1u : 0u;
    const unsigned m1 = load_mask(kmask, base + 1, fmt) ? 1u : 0u;
    const unsigned m2 = load_mask(kmask, base + 2, fmt) ? 1u : 0u;
    const unsigned m3 = load_mask(kmask, base + 3, fmt) ? 1u : 0u;
    kmp_lds[t] = m0 | (m1 << 8) | (m2 << 16) | (m3 << 24);
  }
  for (int i = t; i < 1024; i += 512) sWo[i >> 5][i & 31] = Wo[i];
  if (t < 32) srw[t] = rmsw[t];
  if (t < 16) qmS[t] = load_mask(qmask, (long)rowbase + t, fmt);
  if (t == 0) {
    float a = 0.f, c2 = 0.f;
#pragma unroll
    for (int i = 0; i < 16; ++i) {
      a += lq1[i] * lk1[i];
      c2 += lq2[i] * lk2[i];
    }
    slam = expf(a) - expf(c2) + kLamInit;
  }
  __syncthreads();

  const int wb = w * 128;  // this wave's S-range base
  const short8v z8 = {0, 0, 0, 0, 0, 0, 0, 0};
  const f32x4 zf = {0.f, 0.f, 0.f, 0.f};

  // B-frag: Q columns (lanes<32: k=0..15 <-> head dims)
  short8v qa[2] = {z8, z8};
  if (lane < 32) {
#pragma unroll
    for (int h = 0; h < 2; ++h)
      qa[h] =
          *(const short8v*)&Qbf[((size_t)(rowbase + r15)) * 32 + h * 16 + g * 8];
  }

  // ---- QK^T swapped: D[s=g*4+jj][q=r15] ----
  f32x4 acc[8][2];
#pragma unroll
  for (int c = 0; c < 8; ++c) {
#pragma unroll
    for (int h = 0; h < 2; ++h) {
      short8v kb = z8;
      if (lane < 32)
        kb = *(const short8v*)&Kbf[((size_t)(kvb + wb + c * 16 + r15)) * 32 +
                                   h * 16 + g * 8];
      acc[c][h] = __builtin_amdgcn_mfma_f32_16x16x32_bf16(kb, qa[h], zf, 0, 0, 0);
    }
  }

  unsigned kmp[8];
#pragma unroll
  for (int c = 0; c < 8; ++c) kmp[c] = kmp_lds[(wb >> 2) + c * 4 + g];
  const int qm = qmS[r15];

  // ---- per-(q,h) max over this wave's 128 s ----
  float fm[2], fi[2];
#pragma unroll
  for (int h = 0; h < 2; ++h) {
    float m = -3.0e38f;
#pragma unroll
    for (int c = 0; c < 8; ++c)
#pragma unroll
      for (int jj = 0; jj < 4; ++jj) {
        const float v = ((kmp[c] >> (8 * jj)) & 1u) ? acc[c][h][jj] : kNegBig;
        m = fmaxf(m, v);
      }
    m = fmaxf(m, __shfl_xor(m, 16));
    m = fmaxf(m, __shfl_xor(m, 32));
    if (lane < 16) redm[w][h][lane] = m;
  }
  __syncthreads();
#pragma unroll
  for (int h = 0; h < 2; ++h) {
    float m = -3.0e38f;
#pragma unroll
    for (int ww = 0; ww < 8; ++ww) m = fmaxf(m, redm[ww][h][r15]);
    fm[h] = m;
  }

  // ---- exp2 in place + sum ----
#pragma unroll
  for (int h = 0; h < 2; ++h) {
    float s = 0.f;
#pragma unroll
    for (int c = 0; c < 8; ++c)
#pragma unroll
      for (int jj = 0; jj < 4; ++jj) {
        const float v = ((kmp[c] >> (8 * jj)) & 1u) ? acc[c][h][jj] : kNegBig;
        const float e = fast_exp2(v - fm[h]);
        acc[c][h][jj] = e;
        s += e;
      }
    s += __shfl_xor(s, 16);
    s += __shfl_xor(s, 32);
    if (lane < 16) reds[w][h][lane] = s;
  }
  __syncthreads();
#pragma unroll
  for (int h = 0; h < 2; ++h) {
    float s = 0.f;
#pragma unroll
    for (int ww = 0; ww < 8; ++ww) s += reds[ww][h][r15];
    fi[h] = 1.f / (s + 1e-8f);
  }

  // ---- d = a0 - lam*a1 + min ----
  const float lam = slam;
  float rmin;
  {
    float dm = 3.0e38f;
#pragma unroll
    for (int c = 0; c < 8; ++c)
#pragma unroll
      for (int jj = 0; jj < 4; ++jj) {
        const float d = acc[c][0][jj] * fi[0] - lam * acc[c][1][jj] * fi[1];
        acc[c][0][jj] = d;
        dm = fminf(dm, d);
      }
    dm = fminf(dm, __shfl_xor(dm, 16));
    dm = fminf(dm, __shfl_xor(dm, 32));
    if (lane < 16) redn[w][lane] = dm;
  }
  __syncthreads();
  {
    float m = 3.0e38f;
#pragma unroll
    for (int ww = 0; ww < 8; ++ww) m = fminf(m, redn[ww][r15]);
    rmin = m;
  }

  // ---- final diff: nt float4 store + bf16x4 LDS stage ----
#pragma unroll
  for (int c = 0; c < 8; ++c) {
    f32x4 fd;
#pragma unroll
    for (int jj = 0; jj < 4; ++jj) {
      const int km = (kmp[c] >> (8 * jj)) & 1u;
      fd[jj] = (qm && km) ? acc[c][0][jj] - rmin + 1e-5f : 0.f;
    }
    const int scol = wb + c * 16 + g * 4;
    __builtin_nontemporal_store(
        fd, (f32x4*)&diff[((size_t)(rowbase + r15)) * kS + scol]);
    uint2v p;
    p.x = (unsigned)f2bf(fd[0]) | ((unsigned)f2bf(fd[1]) << 16);
    p.y = (unsigned)f2bf(fd[2]) | ((unsigned)f2bf(fd[3]) << 16);
    *(uint2v*)&dlds[r15 * 1040 + scol] = p;
  }
  __syncthreads();

  // ---- PV: A = d' [q][s], B = Vt[e][s] ----
  f32x4 pv[2] = {zf, zf};
#pragma unroll
  for (int kc = 0; kc < 4; ++kc) {
    const int soff = wb + kc * 32 + g * 8;
    const short8v av = *(const short8v*)&dlds[r15 * 1040 + soff];
#pragma unroll
    for (int n = 0; n < 2; ++n) {
      const short8v bv =
          *(const short8v*)&Vt[((size_t)(b * 32 + n * 16 + r15)) * kS + soff];
      pv[n] = __builtin_amdgcn_mfma_f32_16x16x32_bf16(av, bv, pv[n], 0, 0, 0);
    }
  }
#pragma unroll
  for (int n = 0; n < 2; ++n)
#pragma unroll
    for (int jj = 0; jj < 4; ++jj)
      pvred[w][g * 4 + jj][n * 16 + r15] = pv[n][jj];
  __syncthreads();

  // ---- epilogue: reduce 8 waves, RMSNorm, @Wo ----
  {
    const int row = t >> 5;
    const int col = t & 31;
    float ao = 0.f;
#pragma unroll
    for (int ww = 0; ww < 8; ++ww) ao += pvred[ww][row][col];
    float ss = ao * ao;
#pragma unroll
    for (int off = 16; off >= 1; off >>= 1) ss += __shfl_xor(ss, off);
    const float rms = 1.0f / sqrtf(ss * (1.f / 32.f) + 1e-5f);
    aos[row][col] = ao * rms * srw[col] * kOutScale;
  }
  __syncthreads();
  {
    const int row = t >> 5;
    const int col = t & 31;
    float o = 0.f;
#pragma unroll
    for (int e = 0; e < 32; ++e) o += aos[row][e] * sWo[e][col];
    out[((size_t)(rowbase + row)) * 32 + col] = o;
  }
}

}  // namespace

extern "C" void kernel_launch(void* const* d_in, const int* in_sizes, int n_in,
                              void* d_out, int out_size, void* d_ws,
                              size_t ws_size, hipStream_t stream) {
  const float* query = (const float*)d_in[0];
  const float* key = (const float*)d_in[1];
  const void* qmask = d_in[2];
  const void* kmask = d_in[3];
  const float* Wq = (const float*)d_in[4];
  const float* Wk = (const float*)d_in[5];
  const float* Wv = (const float*)d_in[6];
  const float* Wo = (const float*)d_in[7];
  const float* lq1 = (const float*)d_in[8];
  const float* lk1 = (const float*)d_in[9];
  const float* lq2 = (const float*)d_in[10];
  const float* lk2 = (const float*)d_in[11];
  const float* rmsw = (const float*)d_in[12];

  unsigned short* Qbf = (unsigned short*)d_ws;            // [B*L,32]
  unsigned short* Kbf = Qbf + (size_t)kB * kL * 32;       // [B*S,32]
  unsigned short* Vt = Kbf + (size_t)kB * kS * 32;        // [B,32,S]
  unsigned short* WkT = Vt + (size_t)kB * kS * 32;        // [32,768]
  unsigned short* WvT = WkT + (size_t)32 * 768;           // [32,768]
  int* mflag = (int*)(WvT + (size_t)32 * 768);

  float* outp = (float*)d_out;
  float* diffp = outp + (size_t)kB * kL * 32;

  detect_mask_fmt_kernel<<<dim3(1), dim3(256), 0, stream>>>(
      (const unsigned char*)qmask, mflag);
  prep_wt_kernel<<<dim3(192), dim3(256), 0, stream>>>(Wk, Wv, WkT, WvT);
  proj_q_kernel<<<dim3(kB * kL / 64), dim3(256), 0, stream>>>(query, Wq, Qbf);
  proj_kv_kernel<<<dim3(kB * kS / 64), dim3(256), 0, stream>>>(key, WkT, WvT,
                                                               Kbf, Vt);
  attn_kernel<<<dim3(kB * (kL / 16)), dim3(512), 0, stream>>>(
      Qbf, Kbf, Vt, qmask, kmask, lq1, lk1, lq2, lk2, rmsw, Wo, mflag, outp,
      diffp);
}

// Round 7
// 141.188 us; speedup vs baseline: 4.5076x; 1.1273x over previous
//
#include <hip/hip_runtime.h>

namespace {

typedef __attribute__((ext_vector_type(8))) short short8v;
typedef __attribute__((ext_vector_type(4))) float f32x4;
typedef __attribute__((ext_vector_type(4))) unsigned int uint4v;

constexpr int kB = 8;
constexpr int kS = 1024;
constexpr int kSUB = 768;
constexpr int kL = 4096;                                   // P*G
constexpr float kQScale = 0.25f * 1.44269504088896340736f; // SCALING*log2(e)
constexpr float kLamInit = 0.2f;
constexpr float kOutScale = 0.8f;
constexpr float kNegBig = -1e20f;

__device__ __forceinline__ unsigned short f2bf(float x) {
  unsigned u = __float_as_uint(x);
  return (unsigned short)((u + 0x7FFFu + ((u >> 16) & 1u)) >> 16);
}

__device__ __forceinline__ float fast_exp2(float x) {
#if __has_builtin(__builtin_amdgcn_exp2f)
  return __builtin_amdgcn_exp2f(x);
#else
  return exp2f(x);
#endif
}

__device__ __forceinline__ int load_mask(const void* p, long i, int fmt) {
  if (fmt == 1) return (int)((const unsigned char*)p)[i];
  if (fmt == 2) return (int)(((const int*)p)[2 * i] != 0);
  return ((const int*)p)[i];
}

// ---------------------------------------------------------------------------
// prep: blocks 0..191 transpose Wk/Wv to bf16 [c][k]; block 192 detects mask
// layout (flag: 0=int32, 1=u8, 2=int64).
// ---------------------------------------------------------------------------
__global__ __launch_bounds__(256) void prep_kernel(
    const float* __restrict__ Wk, const float* __restrict__ Wv,
    const unsigned char* __restrict__ qm, unsigned short* __restrict__ WkT,
    unsigned short* __restrict__ WvT, int* __restrict__ flag) {
  if (blockIdx.x < 192) {
    int idx = blockIdx.x * 256 + threadIdx.x;
    if (idx < 24576) {
      const int k = idx >> 5, c = idx & 31;
      WkT[c * 768 + k] = f2bf(Wk[idx]);
    } else {
      idx -= 24576;
      const int k = idx >> 5, c = idx & 31;
      WvT[c * 768 + k] = f2bf(Wv[idx]);
    }
  } else {
    __shared__ int any14, any47;
    if (threadIdx.x == 0) { any14 = 0; any47 = 0; }
    __syncthreads();
    int l14 = 0, l47 = 0;
    for (int i = threadIdx.x; i < 16384; i += 256) {
      const unsigned char v = qm[i];
      if (v && (i & 3)) l14 = 1;
      if (v && ((i & 7) >= 4)) l47 = 1;
    }
    if (l14) atomicOr(&any14, 1);
    if (l47) atomicOr(&any47, 1);
    __syncthreads();
    if (threadIdx.x == 0) *flag = any14 ? 1 : (any47 ? 0 : 2);
  }
}

// ---------------------------------------------------------------------------
// K/V projection via MFMA: 16 rows/block, 64 threads (1 wave), K=768.
// Kbf[r][e]; Vt[b][e][s].
// ---------------------------------------------------------------------------
__global__ __launch_bounds__(64) void proj_kv_kernel(
    const float* __restrict__ key, const unsigned short* __restrict__ WkT,
    const unsigned short* __restrict__ WvT, unsigned short* __restrict__ Kbf,
    unsigned short* __restrict__ Vt) {
  const int t = threadIdx.x;
  const int r15 = t & 15, g = t >> 4;
  const int row = blockIdx.x * 16 + r15;
  const float* kp = &key[(size_t)row * kSUB];
  const f32x4 zf = {0.f, 0.f, 0.f, 0.f};
  f32x4 aK0 = zf, aK1 = zf, aV0 = zf, aV1 = zf;
#pragma unroll 4
  for (int ks = 0; ks < kSUB; ks += 32) {
    const f32x4 lo = *(const f32x4*)&kp[ks + g * 8];
    const f32x4 hi = *(const f32x4*)&kp[ks + g * 8 + 4];
    short8v a;
#pragma unroll
    for (int j = 0; j < 4; ++j) {
      a[j] = (short)f2bf(lo[j]);
      a[4 + j] = (short)f2bf(hi[j]);
    }
    const short8v bk0 = *(const short8v*)&WkT[(size_t)r15 * 768 + ks + g * 8];
    const short8v bk1 =
        *(const short8v*)&WkT[(size_t)(16 + r15) * 768 + ks + g * 8];
    const short8v bv0 = *(const short8v*)&WvT[(size_t)r15 * 768 + ks + g * 8];
    const short8v bv1 =
        *(const short8v*)&WvT[(size_t)(16 + r15) * 768 + ks + g * 8];
    aK0 = __builtin_amdgcn_mfma_f32_16x16x32_bf16(a, bk0, aK0, 0, 0, 0);
    aK1 = __builtin_amdgcn_mfma_f32_16x16x32_bf16(a, bk1, aK1, 0, 0, 0);
    aV0 = __builtin_amdgcn_mfma_f32_16x16x32_bf16(a, bv0, aV0, 0, 0, 0);
    aV1 = __builtin_amdgcn_mfma_f32_16x16x32_bf16(a, bv1, aV1, 0, 0, 0);
  }
  const int orow = blockIdx.x * 16 + g * 4;
#pragma unroll
  for (int jj = 0; jj < 4; ++jj) {
    const int r = orow + jj;
    Kbf[(size_t)r * 32 + r15] = f2bf(aK0[jj]);
    Kbf[(size_t)r * 32 + 16 + r15] = f2bf(aK1[jj]);
    const int bb = r >> 10, s = r & 1023;
    Vt[((size_t)bb * 32 + r15) * kS + s] = f2bf(aV0[jj]);
    Vt[((size_t)bb * 32 + 16 + r15) * kS + s] = f2bf(aV1[jj]);
  }
}

// ---------------------------------------------------------------------------
// Fused attention (Q-proj + QK + softmax-diff + PV + RMSNorm + Wo).
// 16 q-rows/block, 512 threads (8 waves x 128 s-cols). Diff stores after the
// final barrier (fire-and-forget).
// ---------------------------------------------------------------------------
__global__ __launch_bounds__(512) void attn_kernel(
    const float* __restrict__ query, const float* __restrict__ Wq,
    const unsigned short* __restrict__ Kbf,
    const unsigned short* __restrict__ Vt, const void* __restrict__ qmask,
    const void* __restrict__ kmask, const float* __restrict__ lq1,
    const float* __restrict__ lk1, const float* __restrict__ lq2,
    const float* __restrict__ lk2, const float* __restrict__ rmsw,
    const float* __restrict__ Wo, const int* __restrict__ mflag,
    float* __restrict__ out, float* __restrict__ diff) {
  __shared__ __align__(16) char ubuf[8 * 16 * 34 * 4];  // pvred | sWq+sQi
  __shared__ float sWo[32][32];
  __shared__ unsigned short qlds[16][40];
  __shared__ unsigned kmp_lds[256];
  __shared__ float redm[8][2][16];
  __shared__ float reds[8][2][16];
  __shared__ float redn[8][16];
  __shared__ float srw[32];
  __shared__ int qmS[16];
  __shared__ float slam;

  float* const sWq = (float*)ubuf;                 // [32][32] (k-major)
  float* const sQi = (float*)(ubuf + 4096);        // [16][32]
  float* const pvred = (float*)ubuf;               // [8][16][34]

  const int t = threadIdx.x;
  const int lane = t & 63;
  const int w = t >> 6;
  const int r15 = lane & 15;
  const int g = lane >> 4;
  const int b = blockIdx.x >> 8;
  const int rt = (blockIdx.x & 255) * 16;
  const int rowbase = b * kL + rt;
  const int kvb = b * kS;
  const int fmt = *mflag;

  // ---- stage ----
  if (t < 256) {
    *(f32x4*)(sWq + 4 * t) = *(const f32x4*)(Wq + 4 * t);
    *(f32x4*)(&sWo[0][0] + 4 * t) = *(const f32x4*)(Wo + 4 * t);
    const long base = (long)kvb + 4 * t;
    const unsigned m0 = load_mask(kmask, base + 0, fmt) ? 1u : 0u;
    const unsigned m1 = load_mask(kmask, base + 1, fmt) ? 1u : 0u;
    const unsigned m2 = load_mask(kmask, base + 2, fmt) ? 1u : 0u;
    const unsigned m3 = load_mask(kmask, base + 3, fmt) ? 1u : 0u;
    kmp_lds[t] = m0 | (m1 << 8) | (m2 << 16) | (m3 << 24);
  } else if (t < 384) {
    const int i = t - 256;
    *(f32x4*)(sQi + 4 * i) =
        *(const f32x4*)(query + (size_t)rowbase * 32 + 4 * i);
  }
  if (t < 32) srw[t] = rmsw[t];
  if (t < 16) qmS[t] = load_mask(qmask, (long)rowbase + t, fmt);
  if (t == 0) {
    float a = 0.f, c2 = 0.f;
#pragma unroll
    for (int i = 0; i < 16; ++i) {
      a += lq1[i] * lk1[i];
      c2 += lq2[i] * lk2[i];
    }
    slam = expf(a) - expf(c2) + kLamInit;
  }
  __syncthreads();

  // ---- fused Q projection: qlds[q][e] = bf16(dot * scale) ----
  {
    const int row = t >> 5, col = t & 31;
    float a = 0.f;
#pragma unroll
    for (int k = 0; k < 32; ++k) a += sQi[row * 32 + k] * sWq[k * 32 + col];
    qlds[row][col] = f2bf(a * kQScale);
  }
  __syncthreads();

  const int wb = w * 128;  // this wave's S-range base
  const short8v z8 = {0, 0, 0, 0, 0, 0, 0, 0};
  const f32x4 zf = {0.f, 0.f, 0.f, 0.f};
  const float lam = slam;

  // B-frag: Q columns (lanes<32: k=0..15 <-> head dims; rest zero)
  short8v qa[2] = {z8, z8};
  if (lane < 32) {
#pragma unroll
    for (int h = 0; h < 2; ++h)
      qa[h] = *(const short8v*)&qlds[r15][h * 16 + g * 8];
  }

  // ---- QK^T swapped: D[s = g*4+jj][q = r15] ----
  f32x4 acc[8][2];
#pragma unroll
  for (int c = 0; c < 8; ++c) {
    const unsigned short* kr = &Kbf[((size_t)(kvb + wb + c * 16 + r15)) * 32];
    short8v kb0 = z8, kb1 = z8;
    if (lane < 32) {
      kb0 = *(const short8v*)&kr[g * 8];
      kb1 = *(const short8v*)&kr[16 + g * 8];
    }
    acc[c][0] = __builtin_amdgcn_mfma_f32_16x16x32_bf16(kb0, qa[0], zf, 0, 0, 0);
    acc[c][1] = __builtin_amdgcn_mfma_f32_16x16x32_bf16(kb1, qa[1], zf, 0, 0, 0);
  }

  unsigned kmp[8];
#pragma unroll
  for (int c = 0; c < 8; ++c) kmp[c] = kmp_lds[(wb >> 2) + c * 4 + g];
  const int qm = qmS[r15];

  // ---- mask (stored back) + tree max ----
#pragma unroll
  for (int h = 0; h < 2; ++h) {
    float cm[8];
#pragma unroll
    for (int c = 0; c < 8; ++c) {
      f32x4 v = acc[c][h];
#pragma unroll
      for (int jj = 0; jj < 4; ++jj)
        v[jj] = ((kmp[c] >> (8 * jj)) & 1u) ? v[jj] : kNegBig;
      acc[c][h] = v;
      cm[c] = fmaxf(fmaxf(v[0], v[1]), fmaxf(v[2], v[3]));
    }
    float m = fmaxf(fmaxf(fmaxf(cm[0], cm[1]), fmaxf(cm[2], cm[3])),
                    fmaxf(fmaxf(cm[4], cm[5]), fmaxf(cm[6], cm[7])));
    m = fmaxf(m, __shfl_xor(m, 16));
    m = fmaxf(m, __shfl_xor(m, 32));
    if (lane < 16) redm[w][h][lane] = m;
  }
  __syncthreads();

  float fm[2];
#pragma unroll
  for (int h = 0; h < 2; ++h) {
    const float a0 = fmaxf(redm[0][h][r15], redm[1][h][r15]);
    const float a1 = fmaxf(redm[2][h][r15], redm[3][h][r15]);
    const float a2 = fmaxf(redm[4][h][r15], redm[5][h][r15]);
    const float a3 = fmaxf(redm[6][h][r15], redm[7][h][r15]);
    fm[h] = fmaxf(fmaxf(a0, a1), fmaxf(a2, a3));
  }

  // ---- exp2 in place + tree sum ----
#pragma unroll
  for (int h = 0; h < 2; ++h) {
    float s4[4] = {0.f, 0.f, 0.f, 0.f};
#pragma unroll
    for (int c = 0; c < 8; ++c) {
      f32x4 e;
#pragma unroll
      for (int jj = 0; jj < 4; ++jj) e[jj] = fast_exp2(acc[c][h][jj] - fm[h]);
      acc[c][h] = e;
      s4[c & 3] += (e[0] + e[1]) + (e[2] + e[3]);
    }
    float s = (s4[0] + s4[1]) + (s4[2] + s4[3]);
    s += __shfl_xor(s, 16);
    s += __shfl_xor(s, 32);
    if (lane < 16) reds[w][h][lane] = s;
  }
  __syncthreads();

  float fi[2];
#pragma unroll
  for (int h = 0; h < 2; ++h) {
    const float a0 = reds[0][h][r15] + reds[1][h][r15];
    const float a1 = reds[2][h][r15] + reds[3][h][r15];
    const float a2 = reds[4][h][r15] + reds[5][h][r15];
    const float a3 = reds[6][h][r15] + reds[7][h][r15];
    fi[h] = 1.f / ((a0 + a1) + (a2 + a3) + 1e-8f);
  }

  // ---- d = a0 - lam*a1 (in place) + tree min ----
  const float f0 = fi[0], nf1 = -lam * fi[1];
  {
    float cmn[8];
#pragma unroll
    for (int c = 0; c < 8; ++c) {
      f32x4 d;
#pragma unroll
      for (int jj = 0; jj < 4; ++jj)
        d[jj] = fmaf(acc[c][0][jj], f0, nf1 * acc[c][1][jj]);
      acc[c][0] = d;
      cmn[c] = fminf(fminf(d[0], d[1]), fminf(d[2], d[3]));
    }
    float dm = fminf(fminf(fminf(cmn[0], cmn[1]), fminf(cmn[2], cmn[3])),
                     fminf(fminf(cmn[4], cmn[5]), fminf(cmn[6], cmn[7])));
    dm = fminf(dm, __shfl_xor(dm, 16));
    dm = fminf(dm, __shfl_xor(dm, 32));
    if (lane < 16) redn[w][lane] = dm;
  }
  __syncthreads();

  float rmin;
  {
    const float a0 = fminf(redn[0][r15], redn[1][r15]);
    const float a1 = fminf(redn[2][r15], redn[3][r15]);
    const float a2 = fminf(redn[4][r15], redn[5][r15]);
    const float a3 = fminf(redn[6][r15], redn[7][r15]);
    rmin = fminf(fminf(a0, a1), fminf(a2, a3));
  }

  // ---- fd in regs + packed bf16 words ----
  unsigned pkx[8], pky[8];
#pragma unroll
  for (int c = 0; c < 8; ++c) {
    f32x4 fd;
#pragma unroll
    for (int jj = 0; jj < 4; ++jj) {
      const int km = (kmp[c] >> (8 * jj)) & 1u;
      fd[jj] = (qm && km) ? acc[c][0][jj] - rmin + 1e-5f : 0.f;
    }
    acc[c][0] = fd;
    pkx[c] = (unsigned)f2bf(fd[0]) | ((unsigned)f2bf(fd[1]) << 16);
    pky[c] = (unsigned)f2bf(fd[2]) | ((unsigned)f2bf(fd[3]) << 16);
  }

  // ---- PV: A-frag gathered by in-wave shfl (no LDS). Both chunk parities
  // are broadcast; the DESTINATION selects with hi (shfl operands are
  // evaluated in the source lane's context — round-6 bug).
  f32x4 pv[2] = {zf, zf};
  {
    const int sl0 = ((g & 1) << 5) + r15;  // lane of g_src = 2*(g&1)
    const int sl1 = sl0 + 16;              // lane of g_src+1
    const bool hi = (g >> 1) != 0;
#pragma unroll
    for (int kc = 0; kc < 4; ++kc) {
      const unsigned x0a = (unsigned)__shfl((int)pkx[2 * kc], sl0);
      const unsigned y0a = (unsigned)__shfl((int)pky[2 * kc], sl0);
      const unsigned x0b = (unsigned)__shfl((int)pkx[2 * kc], sl1);
      const unsigned y0b = (unsigned)__shfl((int)pky[2 * kc], sl1);
      const unsigned x1a = (unsigned)__shfl((int)pkx[2 * kc + 1], sl0);
      const unsigned y1a = (unsigned)__shfl((int)pky[2 * kc + 1], sl0);
      const unsigned x1b = (unsigned)__shfl((int)pkx[2 * kc + 1], sl1);
      const unsigned y1b = (unsigned)__shfl((int)pky[2 * kc + 1], sl1);
      uint4v avw;
      avw.x = hi ? x1a : x0a;
      avw.y = hi ? y1a : y0a;
      avw.z = hi ? x1b : x0b;
      avw.w = hi ? y1b : y0b;
      const short8v av = *(const short8v*)&avw;
      const int soff = wb + kc * 32 + g * 8;
#pragma unroll
      for (int n = 0; n < 2; ++n) {
        const short8v bv =
            *(const short8v*)&Vt[((size_t)(b * 32 + n * 16 + r15)) * kS + soff];
        pv[n] = __builtin_amdgcn_mfma_f32_16x16x32_bf16(av, bv, pv[n], 0, 0, 0);
      }
    }
  }
#pragma unroll
  for (int n = 0; n < 2; ++n)
#pragma unroll
    for (int jj = 0; jj < 4; ++jj)
      pvred[w * 544 + (g * 4 + jj) * 34 + n * 16 + r15] = pv[n][jj];
  __syncthreads();

  // ---- diff stores: fire-and-forget (no barrier after) ----
#pragma unroll
  for (int c = 0; c < 8; ++c) {
    const int scol = wb + c * 16 + g * 4;
    *(f32x4*)&diff[((size_t)(rowbase + r15)) * kS + scol] = acc[c][0];
  }

  // ---- epilogue: reduce 8 waves, RMSNorm, @Wo via shfl ----
  {
    const int row = t >> 5, col = t & 31;
    float ao = 0.f;
#pragma unroll
    for (int ww = 0; ww < 8; ++ww) ao += pvred[ww * 544 + row * 34 + col];
    float ss = ao * ao;
#pragma unroll
    for (int off = 16; off >= 1; off >>= 1) ss += __shfl_xor(ss, off);
    const float rms = 1.0f / sqrtf(ss * (1.f / 32.f) + 1e-5f);
    const float nx = ao * rms * srw[col] * kOutScale;
    const int half = lane & 32;
    float o = 0.f;
#pragma unroll
    for (int e = 0; e < 32; ++e) o += __shfl(nx, half + e) * sWo[e][col];
    out[((size_t)(rowbase + row)) * 32 + col] = o;
  }
}

}  // namespace

extern "C" void kernel_launch(void* const* d_in, const int* in_sizes, int n_in,
                              void* d_out, int out_size, void* d_ws,
                              size_t ws_size, hipStream_t stream) {
  const float* query = (const float*)d_in[0];
  const float* key = (const float*)d_in[1];
  const void* qmask = d_in[2];
  const void* kmask = d_in[3];
  const float* Wq = (const float*)d_in[4];
  const float* Wk = (const float*)d_in[5];
  const float* Wv = (const float*)d_in[6];
  const float* Wo = (const float*)d_in[7];
  const float* lq1 = (const float*)d_in[8];
  const float* lk1 = (const float*)d_in[9];
  const float* lq2 = (const float*)d_in[10];
  const float* lk2 = (const float*)d_in[11];
  const float* rmsw = (const float*)d_in[12];

  unsigned short* Kbf = (unsigned short*)d_ws;            // [B*S,32]
  unsigned short* Vt = Kbf + (size_t)kB * kS * 32;        // [B,32,S]
  unsigned short* WkT = Vt + (size_t)kB * kS * 32;        // [32,768]
  unsigned short* WvT = WkT + (size_t)32 * 768;           // [32,768]
  int* mflag = (int*)(WvT + (size_t)32 * 768);

  float* outp = (float*)d_out;
  float* diffp = outp + (size_t)kB * kL * 32;

  prep_kernel<<<dim3(193), dim3(256), 0, stream>>>(
      Wk, Wv, (const unsigned char*)qmask, WkT, WvT, mflag);
  proj_kv_kernel<<<dim3(kB * kS / 16), dim3(64), 0, stream>>>(key, WkT, WvT,
                                                              Kbf, Vt);
  attn_kernel<<<dim3(kB * (kL / 16)), dim3(512), 0, stream>>>(
      query, Wq, Kbf, Vt, qmask, kmask, lq1, lk1, lq2, lk2, rmsw, Wo, mflag,
      outp, diffp);
}

// Round 8
// 134.491 us; speedup vs baseline: 4.7320x; 1.0498x over previous
//
#include <hip/hip_runtime.h>

namespace {

typedef __attribute__((ext_vector_type(8))) short short8v;
typedef __attribute__((ext_vector_type(4))) float f32x4;
typedef __attribute__((ext_vector_type(4))) unsigned int uint4v;

constexpr int kB = 8;
constexpr int kS = 1024;
constexpr int kSUB = 768;
constexpr int kL = 4096;                                   // P*G
constexpr float kQScale = 0.25f * 1.44269504088896340736f; // SCALING*log2(e)
constexpr float kLamInit = 0.2f;
constexpr float kOutScale = 0.8f;
constexpr float kShift = 64.f;   // fixed softmax shift (log2 units), safe: |score|<<60

__device__ __forceinline__ unsigned short f2bf(float x) {
  unsigned u = __float_as_uint(x);
  return (unsigned short)((u + 0x7FFFu + ((u >> 16) & 1u)) >> 16);
}

__device__ __forceinline__ float fast_exp2(float x) {
#if __has_builtin(__builtin_amdgcn_exp2f)
  return __builtin_amdgcn_exp2f(x);
#else
  return exp2f(x);
#endif
}

__device__ __forceinline__ int load_mask(const void* p, long i, int fmt) {
  if (fmt == 1) return (int)((const unsigned char*)p)[i];
  if (fmt == 2) return (int)(((const int*)p)[2 * i] != 0);
  return ((const int*)p)[i];
}

// ---------------------------------------------------------------------------
// prep: blocks 0..191 transpose Wk/Wv to bf16 [c][k]; block 192 detects mask
// layout (flag: 0=int32, 1=u8, 2=int64).
// ---------------------------------------------------------------------------
__global__ __launch_bounds__(256) void prep_kernel(
    const float* __restrict__ Wk, const float* __restrict__ Wv,
    const unsigned char* __restrict__ qm, unsigned short* __restrict__ WkT,
    unsigned short* __restrict__ WvT, int* __restrict__ flag) {
  if (blockIdx.x < 192) {
    int idx = blockIdx.x * 256 + threadIdx.x;
    if (idx < 24576) {
      const int k = idx >> 5, c = idx & 31;
      WkT[c * 768 + k] = f2bf(Wk[idx]);
    } else {
      idx -= 24576;
      const int k = idx >> 5, c = idx & 31;
      WvT[c * 768 + k] = f2bf(Wv[idx]);
    }
  } else {
    __shared__ int any14, any47;
    if (threadIdx.x == 0) { any14 = 0; any47 = 0; }
    __syncthreads();
    int l14 = 0, l47 = 0;
    for (int i = threadIdx.x; i < 16384; i += 256) {
      const unsigned char v = qm[i];
      if (v && (i & 3)) l14 = 1;
      if (v && ((i & 7) >= 4)) l47 = 1;
    }
    if (l14) atomicOr(&any14, 1);
    if (l47) atomicOr(&any47, 1);
    __syncthreads();
    if (threadIdx.x == 0) *flag = any14 ? 1 : (any47 ? 0 : 2);
  }
}

// ---------------------------------------------------------------------------
// K/V projection via MFMA: 16 rows/block, 64 threads (1 wave), K=768.
// Kbf[r][e]; Vt[b][e][s].
// ---------------------------------------------------------------------------
__global__ __launch_bounds__(64) void proj_kv_kernel(
    const float* __restrict__ key, const unsigned short* __restrict__ WkT,
    const unsigned short* __restrict__ WvT, unsigned short* __restrict__ Kbf,
    unsigned short* __restrict__ Vt) {
  const int t = threadIdx.x;
  const int r15 = t & 15, g = t >> 4;
  const int row = blockIdx.x * 16 + r15;
  const float* kp = &key[(size_t)row * kSUB];
  const f32x4 zf = {0.f, 0.f, 0.f, 0.f};
  f32x4 aK0 = zf, aK1 = zf, aV0 = zf, aV1 = zf;
#pragma unroll 4
  for (int ks = 0; ks < kSUB; ks += 32) {
    const f32x4 lo = *(const f32x4*)&kp[ks + g * 8];
    const f32x4 hi = *(const f32x4*)&kp[ks + g * 8 + 4];
    short8v a;
#pragma unroll
    for (int j = 0; j < 4; ++j) {
      a[j] = (short)f2bf(lo[j]);
      a[4 + j] = (short)f2bf(hi[j]);
    }
    const short8v bk0 = *(const short8v*)&WkT[(size_t)r15 * 768 + ks + g * 8];
    const short8v bk1 =
        *(const short8v*)&WkT[(size_t)(16 + r15) * 768 + ks + g * 8];
    const short8v bv0 = *(const short8v*)&WvT[(size_t)r15 * 768 + ks + g * 8];
    const short8v bv1 =
        *(const short8v*)&WvT[(size_t)(16 + r15) * 768 + ks + g * 8];
    aK0 = __builtin_amdgcn_mfma_f32_16x16x32_bf16(a, bk0, aK0, 0, 0, 0);
    aK1 = __builtin_amdgcn_mfma_f32_16x16x32_bf16(a, bk1, aK1, 0, 0, 0);
    aV0 = __builtin_amdgcn_mfma_f32_16x16x32_bf16(a, bv0, aV0, 0, 0, 0);
    aV1 = __builtin_amdgcn_mfma_f32_16x16x32_bf16(a, bv1, aV1, 0, 0, 0);
  }
  const int orow = blockIdx.x * 16 + g * 4;
#pragma unroll
  for (int jj = 0; jj < 4; ++jj) {
    const int r = orow + jj;
    Kbf[(size_t)r * 32 + r15] = f2bf(aK0[jj]);
    Kbf[(size_t)r * 32 + 16 + r15] = f2bf(aK1[jj]);
    const int bb = r >> 10, s = r & 1023;
    Vt[((size_t)bb * 32 + r15) * kS + s] = f2bf(aV0[jj]);
    Vt[((size_t)bb * 32 + 16 + r15) * kS + s] = f2bf(aV1[jj]);
  }
}

// ---------------------------------------------------------------------------
// Fused attention: 64 q-rows/block (4 tiles of 16), 512 threads (8 waves x
// 128 s-cols). grid = B * (L/64) = 512 blocks = 2 per CU, one dispatch round.
// No max-reduce (fixed shift); PV cross-wave reduce via LDS atomic adds.
// ---------------------------------------------------------------------------
__global__ __launch_bounds__(512) void attn_kernel(
    const float* __restrict__ query, const float* __restrict__ Wq,
    const unsigned short* __restrict__ Kbf,
    const unsigned short* __restrict__ Vt, const void* __restrict__ qmask,
    const void* __restrict__ kmask, const float* __restrict__ lq1,
    const float* __restrict__ lk1, const float* __restrict__ lq2,
    const float* __restrict__ lk2, const float* __restrict__ rmsw,
    const float* __restrict__ Wo, const int* __restrict__ mflag,
    float* __restrict__ out, float* __restrict__ diff) {
  __shared__ __align__(16) char ubuf[12288];  // {sWq 4KB + sQi 8KB} | pvacc
  __shared__ float sWo[32][32];
  __shared__ unsigned short qlds[64][40];
  __shared__ unsigned kmp_lds[256];
  __shared__ float reds[8][2][16];
  __shared__ float redn[8][16];
  __shared__ float srw[32];
  __shared__ int qmS[64];
  __shared__ float slam;

  float* const sWq = (float*)ubuf;            // [32][32] k-major
  float* const sQi = (float*)(ubuf + 4096);   // [64][32]
  float* const pvacc = (float*)ubuf;          // [64][34] (8704 B)

  const int t = threadIdx.x;
  const int lane = t & 63;
  const int w = t >> 6;
  const int r15 = lane & 15;
  const int g = lane >> 4;
  const int b = blockIdx.x >> 6;
  const int rowbase = b * kL + (blockIdx.x & 63) * 64;
  const int kvb = b * kS;
  const int fmt = *mflag;

  // ---- stage (once per 64 rows) ----
  if (t < 256) {
    *(f32x4*)(sWq + 4 * t) = *(const f32x4*)(Wq + 4 * t);
    *(f32x4*)(&sWo[0][0] + 4 * t) = *(const f32x4*)(Wo + 4 * t);
    const long base = (long)kvb + 4 * t;
    const unsigned m0 = load_mask(kmask, base + 0, fmt) ? 1u : 0u;
    const unsigned m1 = load_mask(kmask, base + 1, fmt) ? 1u : 0u;
    const unsigned m2 = load_mask(kmask, base + 2, fmt) ? 1u : 0u;
    const unsigned m3 = load_mask(kmask, base + 3, fmt) ? 1u : 0u;
    kmp_lds[t] = m0 | (m1 << 8) | (m2 << 16) | (m3 << 24);
  }
  *(f32x4*)(sQi + 4 * t) = *(const f32x4*)(query + (size_t)rowbase * 32 + 4 * t);
  if (t < 64) qmS[t] = load_mask(qmask, (long)rowbase + t, fmt);
  if (t < 32) srw[t] = rmsw[t];
  if (t == 0) {
    float a = 0.f, c2 = 0.f;
#pragma unroll
    for (int i = 0; i < 16; ++i) {
      a += lq1[i] * lk1[i];
      c2 += lq2[i] * lk2[i];
    }
    slam = expf(a) - expf(c2) + kLamInit;
  }
  __syncthreads();

  // ---- fused Q projection: qlds[q][e] = bf16(dot * scale), 64 rows ----
#pragma unroll
  for (int p = 0; p < 4; ++p) {
    const int idx = t + 512 * p;
    const int row = idx >> 5, col = idx & 31;
    float a = 0.f;
#pragma unroll
    for (int k = 0; k < 32; ++k) a += sQi[row * 32 + k] * sWq[k * 32 + col];
    qlds[row][col] = f2bf(a * kQScale);
  }
  __syncthreads();

  // ---- zero pvacc (overlays sWq/sQi; qproj reads are done) ----
  for (int i = t; i < 64 * 34; i += 512) pvacc[i] = 0.f;

  const int wb = w * 128;  // this wave's S-range base
  const short8v z8 = {0, 0, 0, 0, 0, 0, 0, 0};
  const f32x4 zf = {0.f, 0.f, 0.f, 0.f};
  const float lam = slam;

  unsigned kmp[8];
#pragma unroll
  for (int c = 0; c < 8; ++c) kmp[c] = kmp_lds[(wb >> 2) + c * 4 + g];

  const int sl0 = ((g & 1) << 5) + r15;  // PV gather source lanes
  const int sl1 = sl0 + 16;
  const bool hi = (g >> 1) != 0;

  for (int qt = 0; qt < 4; ++qt) {
    const int lr0 = qt * 16;
    const int rb = rowbase + lr0;

    // B-frag: Q columns (lanes<32 active)
    short8v qa0 = z8, qa1 = z8;
    if (lane < 32) {
      qa0 = *(const short8v*)&qlds[lr0 + r15][g * 8];
      qa1 = *(const short8v*)&qlds[lr0 + r15][16 + g * 8];
    }

    // ---- QK^T swapped: D[s = g*4+jj][q = r15] ----
    f32x4 acc[8][2];
#pragma unroll
    for (int c = 0; c < 8; ++c) {
      const unsigned short* kr =
          &Kbf[((size_t)(kvb + wb + c * 16 + r15)) * 32];
      short8v kb0 = z8, kb1 = z8;
      if (lane < 32) {
        kb0 = *(const short8v*)&kr[g * 8];
        kb1 = *(const short8v*)&kr[16 + g * 8];
      }
      acc[c][0] =
          __builtin_amdgcn_mfma_f32_16x16x32_bf16(kb0, qa0, zf, 0, 0, 0);
      acc[c][1] =
          __builtin_amdgcn_mfma_f32_16x16x32_bf16(kb1, qa1, zf, 0, 0, 0);
    }
    const int qm = qmS[lr0 + r15];

    // ---- exp2(v - 64) masked, in place + tree sum (NO max reduce) ----
#pragma unroll
    for (int h = 0; h < 2; ++h) {
      float s4[4] = {0.f, 0.f, 0.f, 0.f};
#pragma unroll
      for (int c = 0; c < 8; ++c) {
        f32x4 e;
#pragma unroll
        for (int jj = 0; jj < 4; ++jj) {
          float ev = fast_exp2(acc[c][h][jj] - kShift);
          e[jj] = ((kmp[c] >> (8 * jj)) & 1u) ? ev : 0.f;
        }
        acc[c][h] = e;
        s4[c & 3] += (e[0] + e[1]) + (e[2] + e[3]);
      }
      float s = (s4[0] + s4[1]) + (s4[2] + s4[3]);
      s += __shfl_xor(s, 16);
      s += __shfl_xor(s, 32);
      if (lane < 16) reds[w][h][lane] = s;
    }
    __syncthreads();  // B1

    float fi[2];
#pragma unroll
    for (int h = 0; h < 2; ++h) {
      const float a0 = reds[0][h][r15] + reds[1][h][r15];
      const float a1 = reds[2][h][r15] + reds[3][h][r15];
      const float a2 = reds[4][h][r15] + reds[5][h][r15];
      const float a3 = reds[6][h][r15] + reds[7][h][r15];
      fi[h] = 1.f / ((a0 + a1) + (a2 + a3) + 1e-37f);
    }

    // ---- d = a0 - lam*a1 (in place) + tree min ----
    const float f0 = fi[0], nf1 = -lam * fi[1];
    {
      float cmn[8];
#pragma unroll
      for (int c = 0; c < 8; ++c) {
        f32x4 d;
#pragma unroll
        for (int jj = 0; jj < 4; ++jj)
          d[jj] = fmaf(acc[c][0][jj], f0, nf1 * acc[c][1][jj]);
        acc[c][0] = d;
        cmn[c] = fminf(fminf(d[0], d[1]), fminf(d[2], d[3]));
      }
      float dm = fminf(fminf(fminf(cmn[0], cmn[1]), fminf(cmn[2], cmn[3])),
                       fminf(fminf(cmn[4], cmn[5]), fminf(cmn[6], cmn[7])));
      dm = fminf(dm, __shfl_xor(dm, 16));
      dm = fminf(dm, __shfl_xor(dm, 32));
      if (lane < 16) redn[w][lane] = dm;
    }
    __syncthreads();  // B2

    float rmin;
    {
      const float a0 = fminf(redn[0][r15], redn[1][r15]);
      const float a1 = fminf(redn[2][r15], redn[3][r15]);
      const float a2 = fminf(redn[4][r15], redn[5][r15]);
      const float a3 = fminf(redn[6][r15], redn[7][r15]);
      rmin = fminf(fminf(a0, a1), fminf(a2, a3));
    }

    // ---- fd: diff stores (fire-and-forget) + packed bf16 ----
    unsigned pkx[8], pky[8];
#pragma unroll
    for (int c = 0; c < 8; ++c) {
      f32x4 fd;
#pragma unroll
      for (int jj = 0; jj < 4; ++jj) {
        const int km = (kmp[c] >> (8 * jj)) & 1u;
        fd[jj] = (qm && km) ? acc[c][0][jj] - rmin + 1e-5f : 0.f;
      }
      const int scol = wb + c * 16 + g * 4;
      *(f32x4*)&diff[((size_t)(rb + r15)) * kS + scol] = fd;
      pkx[c] = (unsigned)f2bf(fd[0]) | ((unsigned)f2bf(fd[1]) << 16);
      pky[c] = (unsigned)f2bf(fd[2]) | ((unsigned)f2bf(fd[3]) << 16);
    }

    // ---- PV: A-frag via in-wave shfl (dest-side parity select) ----
    f32x4 pv[2] = {zf, zf};
#pragma unroll
    for (int kc = 0; kc < 4; ++kc) {
      const unsigned x0a = (unsigned)__shfl((int)pkx[2 * kc], sl0);
      const unsigned y0a = (unsigned)__shfl((int)pky[2 * kc], sl0);
      const unsigned x0b = (unsigned)__shfl((int)pkx[2 * kc], sl1);
      const unsigned y0b = (unsigned)__shfl((int)pky[2 * kc], sl1);
      const unsigned x1a = (unsigned)__shfl((int)pkx[2 * kc + 1], sl0);
      const unsigned y1a = (unsigned)__shfl((int)pky[2 * kc + 1], sl0);
      const unsigned x1b = (unsigned)__shfl((int)pkx[2 * kc + 1], sl1);
      const unsigned y1b = (unsigned)__shfl((int)pky[2 * kc + 1], sl1);
      uint4v avw;
      avw.x = hi ? x1a : x0a;
      avw.y = hi ? y1a : y0a;
      avw.z = hi ? x1b : x0b;
      avw.w = hi ? y1b : y0b;
      const short8v av = *(const short8v*)&avw;
      const int soff = wb + kc * 32 + g * 8;
#pragma unroll
      for (int n = 0; n < 2; ++n) {
        const short8v bv =
            *(const short8v*)&Vt[((size_t)(b * 32 + n * 16 + r15)) * kS + soff];
        pv[n] = __builtin_amdgcn_mfma_f32_16x16x32_bf16(av, bv, pv[n], 0, 0, 0);
      }
    }

    // ---- cross-wave reduce: LDS atomic add (no barrier) ----
#pragma unroll
    for (int n = 0; n < 2; ++n)
#pragma unroll
      for (int jj = 0; jj < 4; ++jj)
        atomicAdd(&pvacc[(lr0 + g * 4 + jj) * 34 + n * 16 + r15], pv[n][jj]);
  }
  __syncthreads();  // all PV adds done

  // ---- epilogue: RMSNorm + @Wo for 64 rows (4 passes) ----
#pragma unroll
  for (int p = 0; p < 4; ++p) {
    const int row = p * 16 + (t >> 5);
    const int col = t & 31;
    const float ao = pvacc[row * 34 + col];
    float ss = ao * ao;
#pragma unroll
    for (int off = 16; off >= 1; off >>= 1) ss += __shfl_xor(ss, off);
    const float rms = 1.0f / sqrtf(ss * (1.f / 32.f) + 1e-5f);
    const float nx = ao * rms * srw[col] * kOutScale;
    const int half = lane & 32;
    float o = 0.f;
#pragma unroll
    for (int e = 0; e < 32; ++e) o += __shfl(nx, half + e) * sWo[e][col];
    out[((size_t)(rowbase + row)) * 32 + col] = o;
  }
}

}  // namespace

extern "C" void kernel_launch(void* const* d_in, const int* in_sizes, int n_in,
                              void* d_out, int out_size, void* d_ws,
                              size_t ws_size, hipStream_t stream) {
  const float* query = (const float*)d_in[0];
  const float* key = (const float*)d_in[1];
  const void* qmask = d_in[2];
  const void* kmask = d_in[3];
  const float* Wq = (const float*)d_in[4];
  const float* Wk = (const float*)d_in[5];
  const float* Wv = (const float*)d_in[6];
  const float* Wo = (const float*)d_in[7];
  const float* lq1 = (const float*)d_in[8];
  const float* lk1 = (const float*)d_in[9];
  const float* lq2 = (const float*)d_in[10];
  const float* lk2 = (const float*)d_in[11];
  const float* rmsw = (const float*)d_in[12];

  unsigned short* Kbf = (unsigned short*)d_ws;            // [B*S,32]
  unsigned short* Vt = Kbf + (size_t)kB * kS * 32;        // [B,32,S]
  unsigned short* WkT = Vt + (size_t)kB * kS * 32;        // [32,768]
  unsigned short* WvT = WkT + (size_t)32 * 768;           // [32,768]
  int* mflag = (int*)(WvT + (size_t)32 * 768);

  float* outp = (float*)d_out;
  float* diffp = outp + (size_t)kB * kL * 32;

  prep_kernel<<<dim3(193), dim3(256), 0, stream>>>(
      Wk, Wv, (const unsigned char*)qmask, WkT, WvT, mflag);
  proj_kv_kernel<<<dim3(kB * kS / 16), dim3(64), 0, stream>>>(key, WkT, WvT,
                                                              Kbf, Vt);
  attn_kernel<<<dim3(kB * (kL / 64)), dim3(512), 0, stream>>>(
      query, Wq, Kbf, Vt, qmask, kmask, lq1, lk1, lq2, lk2, rmsw, Wo, mflag,
      outp, diffp);
}